// Round 8
// baseline (68.179 us; speedup 1.0000x reference)
//
#include <hip/hip_runtime.h>
#include <hip/hip_bf16.h>
#include <utility>

#define DEV static __device__ __forceinline__

typedef __attribute__((ext_vector_type(8))) short bf16x8;
typedef __attribute__((ext_vector_type(4))) float f32x4;

constexpr int KM   = 165;          // number of monomials (deg<=3, 8 complex vars)
constexpr int IT   = 11;           // live i-tiles of 16 (165 -> 176)
constexpr int ITP  = 12;           // padded i-tile count (B layout only)
constexpr int KS   = 6;            // k-steps of 32 -> 192 padded
constexpr int NB   = ITP * KS * 64;
constexpr int ROWS = 64;           // batch rows per block

// ---------------- compile-time POWERS table (itertools.product order) ----------------
struct Pw { unsigned char p[8]; };
struct PwTab { Pw a[KM]; };
constexpr PwTab gen_powers() {
  PwTab t{};
  int idx = 0;
  for (int a0 = 0; a0 <= 3; ++a0)
  for (int a1 = 0; a1 <= 3-a0; ++a1)
  for (int a2 = 0; a2 <= 3-a0-a1; ++a2)
  for (int a3 = 0; a3 <= 3-a0-a1-a2; ++a3)
  for (int a4 = 0; a4 <= 3-a0-a1-a2-a3; ++a4)
  for (int a5 = 0; a5 <= 3-a0-a1-a2-a3-a4; ++a5)
  for (int a6 = 0; a6 <= 3-a0-a1-a2-a3-a4-a5; ++a6)
  for (int a7 = 0; a7 <= 3-a0-a1-a2-a3-a4-a5-a6; ++a7) {
    t.a[idx].p[0] = (unsigned char)a0; t.a[idx].p[1] = (unsigned char)a1;
    t.a[idx].p[2] = (unsigned char)a2; t.a[idx].p[3] = (unsigned char)a3;
    t.a[idx].p[4] = (unsigned char)a4; t.a[idx].p[5] = (unsigned char)a5;
    t.a[idx].p[6] = (unsigned char)a6; t.a[idx].p[7] = (unsigned char)a7;
    ++idx;
  }
  return t;
}
constexpr PwTab PW = gen_powers();

// ---------------- helpers ----------------
DEV unsigned int f2bf(float f) {            // RNE float -> bf16 bits
  unsigned int u = __builtin_bit_cast(unsigned int, f);
  u += 0x7fffu + ((u >> 16) & 1u);
  return u >> 16;
}
DEV unsigned int pack2(float lo, float hi) { return f2bf(lo) | (f2bf(hi) << 16); }
DEV float softplusf(float x) { return (x > 20.f) ? x : log1pf(expf(x)); }

// ---- monomial evaluation: ALL table indices are template params (scratch-proof) ----
template<int JJ, int C>
DEV void mono_step(float& r, float& i,
                   const float (&lx)[8][3], const float (&ly)[8][3]) {
  constexpr int pc = PW.a[JJ].p[C];
  if constexpr (pc > 0) {
    const float ar = lx[C][pc-1], ai = ly[C][pc-1];
    const float tr = r*ar - i*ai;
    i = r*ai + i*ar;
    r = tr;
  }
}
template<int JJ>
DEV void mono_eval(float& mr, float& mi,
                   const float (&lx)[8][3], const float (&ly)[8][3]) {
  float r = 1.f, i = 0.f;
  mono_step<JJ,0>(r,i,lx,ly); mono_step<JJ,1>(r,i,lx,ly);
  mono_step<JJ,2>(r,i,lx,ly); mono_step<JJ,3>(r,i,lx,ly);
  mono_step<JJ,4>(r,i,lx,ly); mono_step<JJ,5>(r,i,lx,ly);
  mono_step<JJ,6>(r,i,lx,ly); mono_step<JJ,7>(r,i,lx,ly);
  mr = r; mi = i;
}
template<int JJ>
DEV void mono_eval_guard(float& r, float& i,
                         const float (&lx)[8][3], const float (&ly)[8][3]) {
  if constexpr (JJ < KM) mono_eval<JJ>(r, i, lx, ly);
  else { r = 0.f; i = 0.f; }
}

// ---- gen: chunk T covers monomials [8T, 8T+8) = k-slice (ks=T>>2, g=T&3) ----
template<int T, int... Us>
DEV void gen8(std::integer_sequence<int, Us...>, float (&mr)[8], float (&mi)[8],
              const float (&lx)[8][3], const float (&ly)[8][3]) {
  (mono_eval_guard<8*T + Us>(mr[Us], mi[Us], lx, ly), ...);
}
template<int T>
DEV void gen_chunk(const float (&lx)[8][3], const float (&ly)[8][3],
                   unsigned int* Xf, unsigned int* Yf, int mf, int r15) {
  constexpr int ksv = T >> 2;
  constexpr int gv  = T & 3;
  float mr[8], mi[8];
  gen8<T>(std::make_integer_sequence<int, 8>{}, mr, mi, lx, ly);
  uint4 ux, uy;
  ux.x = pack2(mr[0], mr[1]); ux.y = pack2(mr[2], mr[3]);
  ux.z = pack2(mr[4], mr[5]); ux.w = pack2(mr[6], mr[7]);
  uy.x = pack2(mi[0], mi[1]); uy.y = pack2(mi[2], mi[3]);
  uy.z = pack2(mi[4], mi[5]); uy.w = pack2(mi[6], mi[7]);
  const unsigned int off = (unsigned int)((mf*6 + ksv)*256 + gv*64 + r15*4);
  *(uint4*)&Xf[off] = ux;
  *(uint4*)&Yf[off] = uy;
}
template<int W, int... Ts>
DEV void gen_seq(std::integer_sequence<int, Ts...>,
                 const float (&lx)[8][3], const float (&ly)[8][3],
                 unsigned int* Xf, unsigned int* Yf, int mf, int r15) {
  (gen_chunk<6*W + Ts>(lx, ly, Xf, Yf, mf, r15), ...);
}
template<int W>
DEV void gen_wave(const float (&lx)[8][3], const float (&ly)[8][3],
                  unsigned int* Xf, unsigned int* Yf, int mf, int r15) {
  gen_seq<W>(std::make_integer_sequence<int, 6>{}, lx, ly, Xf, Yf, mf, r15);
}

// ---------------- prep: conj(L)^T -> bf16 B-operand fragments (triangular) ----------
__global__ void __launch_bounds__(256) poskahler_prep(
    const float* __restrict__ Lre, const float* __restrict__ Lim,
    uint4* __restrict__ bp, uint4* __restrict__ bq) {
  const int tid = blockIdx.x * 256 + threadIdx.x;
  if (tid >= NB) return;
  const int lane = tid & 63;
  const int it = (tid >> 6) / KS;
  const int ks = (tid >> 6) % KS;
  const int j  = it * 16 + (lane & 15);
  const int ib = ks * 32 + ((lane >> 4) << 3);
  float pr[8], qr[8];
#pragma unroll
  for (int e = 0; e < 8; ++e) { pr[e] = 0.f; qr[e] = 0.f; }
  if (j < KM) {
#pragma unroll
    for (int e = 0; e < 8; ++e) {
      const int i = ib + e;
      if (i < KM) {
        if (i > j)      { pr[e] = Lre[i*KM + j]; qr[e] = -Lim[i*KM + j]; }
        else if (i == j){ pr[e] = softplusf(Lre[j*KM + j]) + 0.001f; }
      }
    }
  }
  uint4 up, uq;
  up.x = pack2(pr[0], pr[1]); up.y = pack2(pr[2], pr[3]);
  up.z = pack2(pr[4], pr[5]); up.w = pack2(pr[6], pr[7]);
  uq.x = pack2(qr[0], qr[1]); uq.y = pack2(qr[2], qr[3]);
  uq.z = pack2(qr[4], qr[5]); uq.w = pack2(qr[6], qr[7]);
  bp[tid] = up;
  bq[tid] = uq;
}

// ---------------- main k-loop building blocks (fully static) ----------------
template<int KSv>
DEV void load_tiles(const uint4* __restrict__ bp, const uint4* __restrict__ bq,
                    int wv, int lane, uint4 (&tp)[3], uint4 (&tq)[3]) {
#pragma unroll
  for (int ii = 0; ii < 3; ++ii) {
    const int it = 4*ii + wv;
    if (it <= 2*KSv + 1 && it < IT) {
      const int fs = (it*KS + KSv)*64 + lane;
      tp[ii] = bp[fs];
      tq[ii] = bq[fs];
    }
  }
}

template<int KSv>
DEV void compute_ks(const unsigned int* Xf, const unsigned int* Yf,
                    int wv, int lane,
                    const uint4 (&tp)[3], const uint4 (&tq)[3],
                    f32x4 (&aRe)[3][4], f32x4 (&aIm)[3][4]) {
  if (wv > 2*KSv + 1) return;     // wave-uniform: no live tile at this ks
  bf16x8 xf[4], yf[4];
#pragma unroll
  for (int mf = 0; mf < 4; ++mf) {
    const unsigned int off = (unsigned int)((mf*6 + KSv)*256) + (unsigned int)lane*4;
    xf[mf] = __builtin_bit_cast(bf16x8, *(const uint4*)&Xf[off]);
    yf[mf] = __builtin_bit_cast(bf16x8, *(const uint4*)&Yf[off]);
  }
#pragma unroll
  for (int ii = 0; ii < 3; ++ii) {
    const int it = 4*ii + wv;
    if (it <= 2*KSv + 1 && it < IT) {
      const uint4 up = tp[ii];
      const uint4 uq = tq[ii];
      uint4 un;
      un.x = uq.x ^ 0x80008000u; un.y = uq.y ^ 0x80008000u;
      un.z = uq.z ^ 0x80008000u; un.w = uq.w ^ 0x80008000u;
      const bf16x8 vp = __builtin_bit_cast(bf16x8, up);
      const bf16x8 vq = __builtin_bit_cast(bf16x8, uq);
      const bf16x8 vn = __builtin_bit_cast(bf16x8, un);
#pragma unroll
      for (int mf = 0; mf < 4; ++mf) {
        // wre = P x + Q y ; wim = P y - Q x  — accumulate IN PLACE (no reg copies)
        aRe[ii][mf] = __builtin_amdgcn_mfma_f32_16x16x32_bf16(xf[mf], vp, aRe[ii][mf], 0, 0, 0);
        aRe[ii][mf] = __builtin_amdgcn_mfma_f32_16x16x32_bf16(yf[mf], vq, aRe[ii][mf], 0, 0, 0);
        aIm[ii][mf] = __builtin_amdgcn_mfma_f32_16x16x32_bf16(yf[mf], vp, aIm[ii][mf], 0, 0, 0);
        aIm[ii][mf] = __builtin_amdgcn_mfma_f32_16x16x32_bf16(xf[mf], vn, aIm[ii][mf], 0, 0, 0);
      }
    }
  }
}

// ---------------- main: monomials -> w = L^H z via MFMA -> log(|w|^2) --------------
__global__ void __launch_bounds__(256, 2) poskahler_main(
    const float* __restrict__ q,
    const uint4* __restrict__ bp, const uint4* __restrict__ bq,
    float* __restrict__ out) {
  // fragment-ordered monomial store: region (mf*6+ks)*256 dwords, lane entry lane*4
  __shared__ __align__(16) unsigned int Xf[6144];
  __shared__ __align__(16) unsigned int Yf[6144];
  __shared__ float qpart[4][ROWS];

  const int t     = threadIdx.x;
  const int lane  = t & 63;
  const int wv    = t >> 6;                 // 4 waves
  const int bbase = blockIdx.x * ROWS;
  const int mf_r  = lane >> 4;              // gen: this thread's row -> frag mf
  const int r15   = lane & 15;

  // ---- B-tile prefetch for ks=0,1 (latency hides under gen phase) ----
  uint4 tpA[3] = {}, tqA[3] = {}, tpB[3] = {}, tqB[3] = {};
  load_tiles<0>(bp, bq, wv, lane, tpA, tqA);
  load_tiles<1>(bp, bq, wv, lane, tpB, tqB);

  // ---- monomial generation: wave wv covers monomials [48wv, 48wv+48) of each row --
  {
    const float* qr = q + (size_t)(bbase + lane) * 16;
    const float4 q0 = ((const float4*)qr)[0];
    const float4 q1 = ((const float4*)qr)[1];
    const float4 q2 = ((const float4*)qr)[2];
    const float4 q3 = ((const float4*)qr)[3];
    const float xs[8] = {q0.x,q0.y,q0.z,q0.w,q1.x,q1.y,q1.z,q1.w};
    const float ys[8] = {q2.x,q2.y,q2.z,q2.w,q3.x,q3.y,q3.z,q3.w};
    float lx[8][3], ly[8][3];
#pragma unroll
    for (int c = 0; c < 8; ++c) {
      const float xr = xs[c], yi = ys[c];
      lx[c][0] = xr;             ly[c][0] = yi;
      lx[c][1] = xr*xr - yi*yi;  ly[c][1] = 2.f*xr*yi;
      lx[c][2] = lx[c][1]*xr - ly[c][1]*yi;
      ly[c][2] = lx[c][1]*yi + ly[c][1]*xr;
    }
    switch (wv) {
      case 0: gen_wave<0>(lx, ly, Xf, Yf, mf_r, r15); break;
      case 1: gen_wave<1>(lx, ly, Xf, Yf, mf_r, r15); break;
      case 2: gen_wave<2>(lx, ly, Xf, Yf, mf_r, r15); break;
      default: gen_wave<3>(lx, ly, Xf, Yf, mf_r, r15); break;
    }
  }
  __syncthreads();

  // ---- w = L^H z : ks fully unrolled, double-buffered B tiles ----
  f32x4 aRe[3][4], aIm[3][4];
#pragma unroll
  for (int ii = 0; ii < 3; ++ii)
#pragma unroll
    for (int mf = 0; mf < 4; ++mf) {
      aRe[ii][mf] = (f32x4){0.f,0.f,0.f,0.f};
      aIm[ii][mf] = (f32x4){0.f,0.f,0.f,0.f};
    }

  compute_ks<0>(Xf, Yf, wv, lane, tpA, tqA, aRe, aIm);
  load_tiles<2>(bp, bq, wv, lane, tpA, tqA);
  compute_ks<1>(Xf, Yf, wv, lane, tpB, tqB, aRe, aIm);
  load_tiles<3>(bp, bq, wv, lane, tpB, tqB);
  compute_ks<2>(Xf, Yf, wv, lane, tpA, tqA, aRe, aIm);
  load_tiles<4>(bp, bq, wv, lane, tpA, tqA);
  compute_ks<3>(Xf, Yf, wv, lane, tpB, tqB, aRe, aIm);
  load_tiles<5>(bp, bq, wv, lane, tpB, tqB);
  compute_ks<4>(Xf, Yf, wv, lane, tpA, tqA, aRe, aIm);
  compute_ks<5>(Xf, Yf, wv, lane, tpB, tqB, aRe, aIm);

  // ---- epilogue: quad partial = sum_j |w_j|^2 ----
  float p[4][4];
#pragma unroll
  for (int mf = 0; mf < 4; ++mf)
#pragma unroll
    for (int rr = 0; rr < 4; ++rr) p[mf][rr] = 0.f;

#pragma unroll
  for (int ii = 0; ii < 3; ++ii)
#pragma unroll
    for (int mf = 0; mf < 4; ++mf)
#pragma unroll
      for (int rr = 0; rr < 4; ++rr)
        p[mf][rr] += aRe[ii][mf][rr]*aRe[ii][mf][rr] + aIm[ii][mf][rr]*aIm[ii][mf][rr];

#pragma unroll
  for (int mf = 0; mf < 4; ++mf)
#pragma unroll
    for (int rr = 0; rr < 4; ++rr) {
      float v = p[mf][rr];
      v += __shfl_xor(v, 1);
      v += __shfl_xor(v, 2);
      v += __shfl_xor(v, 4);
      v += __shfl_xor(v, 8);
      p[mf][rr] = v;
    }

  if (r15 == 0) {
    const int g = lane >> 4;
#pragma unroll
    for (int mf = 0; mf < 4; ++mf)
#pragma unroll
      for (int rr = 0; rr < 4; ++rr)
        qpart[wv][mf*16 + 4*g + rr] = p[mf][rr];
  }
  __syncthreads();
  if (t < ROWS) {
    const float quad = qpart[0][t] + qpart[1][t] + qpart[2][t] + qpart[3][t];
    out[bbase + t] = logf(quad + 1e-12f);
  }
}

// ---------------- host ----------------
extern "C" void kernel_launch(void* const* d_in, const int* in_sizes, int n_in,
                              void* d_out, int out_size, void* d_ws, size_t ws_size,
                              hipStream_t stream) {
  const float* q   = (const float*)d_in[0];
  const float* Lre = (const float*)d_in[1];
  const float* Lim = (const float*)d_in[2];
  float* out = (float*)d_out;
  uint4* bp = (uint4*)d_ws;
  uint4* bq = bp + NB;
  const int B = in_sizes[0] / 16;
  poskahler_prep<<<(NB + 255)/256, 256, 0, stream>>>(Lre, Lim, bp, bq);
  poskahler_main<<<B / ROWS, 256, 0, stream>>>(q, bp, bq, out);
}

// Round 10
// 65.254 us; speedup vs baseline: 1.0448x; 1.0448x over previous
//
#include <hip/hip_runtime.h>
#include <hip/hip_bf16.h>
#include <utility>

#define DEV static __device__ __forceinline__

typedef __attribute__((ext_vector_type(8))) short bf16x8;
typedef __attribute__((ext_vector_type(4))) float f32x4;

constexpr int KM   = 165;          // number of monomials (deg<=3, 8 complex vars)
constexpr int IT   = 11;           // live i-tiles of 16 (165 -> 176)
constexpr int ITP  = 12;           // padded i-tile count (B layout only)
constexpr int KS   = 6;            // k-steps of 32 -> 192 padded
constexpr int NB   = ITP * KS * 64;
constexpr int ROWS = 64;           // batch rows per rowset

// ---------------- compile-time POWERS table (itertools.product order) ----------------
struct Pw { unsigned char p[8]; };
struct PwTab { Pw a[KM]; };
constexpr PwTab gen_powers() {
  PwTab t{};
  int idx = 0;
  for (int a0 = 0; a0 <= 3; ++a0)
  for (int a1 = 0; a1 <= 3-a0; ++a1)
  for (int a2 = 0; a2 <= 3-a0-a1; ++a2)
  for (int a3 = 0; a3 <= 3-a0-a1-a2; ++a3)
  for (int a4 = 0; a4 <= 3-a0-a1-a2-a3; ++a4)
  for (int a5 = 0; a5 <= 3-a0-a1-a2-a3-a4; ++a5)
  for (int a6 = 0; a6 <= 3-a0-a1-a2-a3-a4-a5; ++a6)
  for (int a7 = 0; a7 <= 3-a0-a1-a2-a3-a4-a5-a6; ++a7) {
    t.a[idx].p[0] = (unsigned char)a0; t.a[idx].p[1] = (unsigned char)a1;
    t.a[idx].p[2] = (unsigned char)a2; t.a[idx].p[3] = (unsigned char)a3;
    t.a[idx].p[4] = (unsigned char)a4; t.a[idx].p[5] = (unsigned char)a5;
    t.a[idx].p[6] = (unsigned char)a6; t.a[idx].p[7] = (unsigned char)a7;
    ++idx;
  }
  return t;
}
constexpr PwTab PW = gen_powers();

// ---------------- helpers ----------------
DEV unsigned int f2bf(float f) {            // RNE float -> bf16 bits
  unsigned int u = __builtin_bit_cast(unsigned int, f);
  u += 0x7fffu + ((u >> 16) & 1u);
  return u >> 16;
}
DEV unsigned int pack2(float lo, float hi) { return f2bf(lo) | (f2bf(hi) << 16); }
DEV float softplusf(float x) { return (x > 20.f) ? x : log1pf(expf(x)); }

// ---- monomial evaluation: ALL table indices are template params (scratch-proof) ----
template<int JJ, int C>
DEV void mono_step(float& r, float& i,
                   const float (&lx)[8][3], const float (&ly)[8][3]) {
  constexpr int pc = PW.a[JJ].p[C];
  if constexpr (pc > 0) {
    const float ar = lx[C][pc-1], ai = ly[C][pc-1];
    const float tr = r*ar - i*ai;
    i = r*ai + i*ar;
    r = tr;
  }
}
template<int JJ>
DEV void mono_eval(float& mr, float& mi,
                   const float (&lx)[8][3], const float (&ly)[8][3]) {
  float r = 1.f, i = 0.f;
  mono_step<JJ,0>(r,i,lx,ly); mono_step<JJ,1>(r,i,lx,ly);
  mono_step<JJ,2>(r,i,lx,ly); mono_step<JJ,3>(r,i,lx,ly);
  mono_step<JJ,4>(r,i,lx,ly); mono_step<JJ,5>(r,i,lx,ly);
  mono_step<JJ,6>(r,i,lx,ly); mono_step<JJ,7>(r,i,lx,ly);
  mr = r; mi = i;
}
template<int JJ>
DEV void mono_eval_guard(float& r, float& i,
                         const float (&lx)[8][3], const float (&ly)[8][3]) {
  if constexpr (JJ < KM) mono_eval<JJ>(r, i, lx, ly);
  else { r = 0.f; i = 0.f; }
}

// ---- gen: chunk T covers monomials [8T, 8T+8) = k-slice (ks=T>>2, g=T&3) ----
template<int T, int... Us>
DEV void gen8(std::integer_sequence<int, Us...>, float (&mr)[8], float (&mi)[8],
              const float (&lx)[8][3], const float (&ly)[8][3]) {
  (mono_eval_guard<8*T + Us>(mr[Us], mi[Us], lx, ly), ...);
}
template<int T>
DEV void gen_chunk(const float (&lx)[8][3], const float (&ly)[8][3],
                   unsigned int* Xf, unsigned int* Yf, int mf, int r15) {
  constexpr int ksv = T >> 2;
  constexpr int gv  = T & 3;
  float mr[8], mi[8];
  gen8<T>(std::make_integer_sequence<int, 8>{}, mr, mi, lx, ly);
  uint4 ux, uy;
  ux.x = pack2(mr[0], mr[1]); ux.y = pack2(mr[2], mr[3]);
  ux.z = pack2(mr[4], mr[5]); ux.w = pack2(mr[6], mr[7]);
  uy.x = pack2(mi[0], mi[1]); uy.y = pack2(mi[2], mi[3]);
  uy.z = pack2(mi[4], mi[5]); uy.w = pack2(mi[6], mi[7]);
  const unsigned int off = (unsigned int)((mf*6 + ksv)*256 + gv*64 + r15*4);
  *(uint4*)&Xf[off] = ux;
  *(uint4*)&Yf[off] = uy;
}
template<int W, int... Ts>
DEV void gen_seq(std::integer_sequence<int, Ts...>,
                 const float (&lx)[8][3], const float (&ly)[8][3],
                 unsigned int* Xf, unsigned int* Yf, int mf, int r15) {
  (gen_chunk<6*W + Ts>(lx, ly, Xf, Yf, mf, r15), ...);
}
template<int W>
DEV void gen_wave(const float (&lx)[8][3], const float (&ly)[8][3],
                  unsigned int* Xf, unsigned int* Yf, int mf, int r15) {
  gen_seq<W>(std::make_integer_sequence<int, 6>{}, lx, ly, Xf, Yf, mf, r15);
}

// ---- full rowset generation for one gen wave (r4-verbatim inner body) ----
DEV void gen_rowset(const float* __restrict__ q, int rs, int lane, int gw,
                    unsigned int* Xb, unsigned int* Yb, int mf_r, int r15) {
  const float* qr = q + ((size_t)rs * ROWS + lane) * 16;
  const float4 q0 = ((const float4*)qr)[0];
  const float4 q1 = ((const float4*)qr)[1];
  const float4 q2 = ((const float4*)qr)[2];
  const float4 q3 = ((const float4*)qr)[3];
  const float xs[8] = {q0.x,q0.y,q0.z,q0.w,q1.x,q1.y,q1.z,q1.w};
  const float ys[8] = {q2.x,q2.y,q2.z,q2.w,q3.x,q3.y,q3.z,q3.w};
  float lx[8][3], ly[8][3];
#pragma unroll
  for (int c = 0; c < 8; ++c) {
    const float xr = xs[c], yi = ys[c];
    lx[c][0] = xr;             ly[c][0] = yi;
    lx[c][1] = xr*xr - yi*yi;  ly[c][1] = 2.f*xr*yi;
    lx[c][2] = lx[c][1]*xr - ly[c][1]*yi;
    ly[c][2] = lx[c][1]*yi + ly[c][1]*xr;
  }
  switch (gw) {
    case 0: gen_wave<0>(lx, ly, Xb, Yb, mf_r, r15); break;
    case 1: gen_wave<1>(lx, ly, Xb, Yb, mf_r, r15); break;
    case 2: gen_wave<2>(lx, ly, Xb, Yb, mf_r, r15); break;
    default: gen_wave<3>(lx, ly, Xb, Yb, mf_r, r15); break;
  }
}

// ---------------- prep: conj(L)^T -> bf16 B-operand fragments (triangular) ----------
__global__ void __launch_bounds__(256) poskahler_prep(
    const float* __restrict__ Lre, const float* __restrict__ Lim,
    uint4* __restrict__ bp, uint4* __restrict__ bq) {
  const int tid = blockIdx.x * 256 + threadIdx.x;
  if (tid >= NB) return;
  const int lane = tid & 63;
  const int it = (tid >> 6) / KS;
  const int ks = (tid >> 6) % KS;
  const int j  = it * 16 + (lane & 15);
  const int ib = ks * 32 + ((lane >> 4) << 3);
  float pr[8], qr[8];
#pragma unroll
  for (int e = 0; e < 8; ++e) { pr[e] = 0.f; qr[e] = 0.f; }
  if (j < KM) {
#pragma unroll
    for (int e = 0; e < 8; ++e) {
      const int i = ib + e;
      if (i < KM) {
        if (i > j)      { pr[e] = Lre[i*KM + j]; qr[e] = -Lim[i*KM + j]; }
        else if (i == j){ pr[e] = softplusf(Lre[j*KM + j]) + 0.001f; }
      }
    }
  }
  uint4 up, uq;
  up.x = pack2(pr[0], pr[1]); up.y = pack2(pr[2], pr[3]);
  up.z = pack2(pr[4], pr[5]); up.w = pack2(pr[6], pr[7]);
  uq.x = pack2(qr[0], qr[1]); uq.y = pack2(qr[2], qr[3]);
  uq.z = pack2(qr[4], qr[5]); uq.w = pack2(qr[6], qr[7]);
  bp[tid] = up;
  bq[tid] = uq;
}

// ---------------- main k-loop building blocks (r4-verbatim) ----------------
template<int KSv>
DEV void load_tiles(const uint4* __restrict__ bp, const uint4* __restrict__ bq,
                    int wv, int lane, uint4 (&tp)[3], uint4 (&tq)[3]) {
#pragma unroll
  for (int ii = 0; ii < 3; ++ii) {
    const int it = 4*ii + wv;
    if (it <= 2*KSv + 1 && it < IT) {
      const int fs = (it*KS + KSv)*64 + lane;
      tp[ii] = bp[fs];
      tq[ii] = bq[fs];
    }
  }
}

template<int KSv>
DEV void compute_ks(const unsigned int* Xf, const unsigned int* Yf,
                    int wv, int lane,
                    const uint4 (&tp)[3], const uint4 (&tq)[3],
                    float (&aRe)[3][4][4], float (&aIm)[3][4][4]) {
  if (wv > 2*KSv + 1) return;     // wave-uniform: no live tile at this ks
  bf16x8 xf[4], yf[4];
#pragma unroll
  for (int mf = 0; mf < 4; ++mf) {
    const unsigned int off = (unsigned int)((mf*6 + KSv)*256) + (unsigned int)lane*4;
    xf[mf] = __builtin_bit_cast(bf16x8, *(const uint4*)&Xf[off]);
    yf[mf] = __builtin_bit_cast(bf16x8, *(const uint4*)&Yf[off]);
  }
#pragma unroll
  for (int ii = 0; ii < 3; ++ii) {
    const int it = 4*ii + wv;
    if (it <= 2*KSv + 1 && it < IT) {
      const uint4 up = tp[ii];
      const uint4 uq = tq[ii];
      uint4 un;
      un.x = uq.x ^ 0x80008000u; un.y = uq.y ^ 0x80008000u;
      un.z = uq.z ^ 0x80008000u; un.w = uq.w ^ 0x80008000u;
      const bf16x8 vp = __builtin_bit_cast(bf16x8, up);
      const bf16x8 vq = __builtin_bit_cast(bf16x8, uq);
      const bf16x8 vn = __builtin_bit_cast(bf16x8, un);
#pragma unroll
      for (int mf = 0; mf < 4; ++mf) {
        f32x4 cre = { aRe[ii][mf][0], aRe[ii][mf][1], aRe[ii][mf][2], aRe[ii][mf][3] };
        f32x4 cim = { aIm[ii][mf][0], aIm[ii][mf][1], aIm[ii][mf][2], aIm[ii][mf][3] };
        // wre = P x + Q y ; wim = P y - Q x
        cre = __builtin_amdgcn_mfma_f32_16x16x32_bf16(xf[mf], vp, cre, 0, 0, 0);
        cre = __builtin_amdgcn_mfma_f32_16x16x32_bf16(yf[mf], vq, cre, 0, 0, 0);
        cim = __builtin_amdgcn_mfma_f32_16x16x32_bf16(yf[mf], vp, cim, 0, 0, 0);
        cim = __builtin_amdgcn_mfma_f32_16x16x32_bf16(xf[mf], vn, cim, 0, 0, 0);
#pragma unroll
        for (int rr = 0; rr < 4; ++rr) { aRe[ii][mf][rr] = cre[rr]; aIm[ii][mf][rr] = cim[rr]; }
      }
    }
  }
}

// ---------------- main: producer(gen)/consumer(MFMA) wave-specialized pipeline -----
__global__ void __launch_bounds__(512, 2) poskahler_main(
    const float* __restrict__ q,
    const uint4* __restrict__ bp, const uint4* __restrict__ bq,
    float* __restrict__ out, int nrs) {
  // two monomial buffers, fragment-ordered: region (mf*6+ks)*256 dwords, entry lane*4
  __shared__ __align__(16) unsigned int Xls[2*6144];
  __shared__ __align__(16) unsigned int Yls[2*6144];
  __shared__ float qp[2][4][ROWS];

  const int t     = threadIdx.x;
  const int lane  = t & 63;
  const int wv8   = t >> 6;           // 0..7
  const bool genw = (wv8 >= 4);       // waves 4..7 = producers
  const int wv    = wv8 & 3;          // compute-wave id / gen-wave id
  const int mf_r  = lane >> 4;
  const int r15   = lane & 15;
  const int gstr  = gridDim.x;

  uint4 tpA[3] = {}, tqA[3] = {}, tpB[3] = {}, tqB[3] = {};
  int r = blockIdx.x;                 // current compute rowset
  int i = 0;                          // iteration counter (buffer parity)

  // ---- prologue: producers build rowset r into buf0; consumers preload B ks0/1 ----
  if (genw) {
    gen_rowset(q, r, lane, wv, Xls, Yls, mf_r, r15);
  } else {
    load_tiles<0>(bp, bq, wv, lane, tpA, tqA);
    load_tiles<1>(bp, bq, wv, lane, tpB, tqB);
  }

  while (true) {
    __syncthreads();                  // buf[i&1] ready; qp[(i-1)&1] ready
    const int par = i & 1;
    if (!genw) {
      const unsigned int* Xb = Xls + par*6144;
      const unsigned int* Yb = Yls + par*6144;
      float aRe[3][4][4], aIm[3][4][4];
#pragma unroll
      for (int ii = 0; ii < 3; ++ii)
#pragma unroll
        for (int mf = 0; mf < 4; ++mf)
#pragma unroll
          for (int rr = 0; rr < 4; ++rr) { aRe[ii][mf][rr] = 0.f; aIm[ii][mf][rr] = 0.f; }

      compute_ks<0>(Xb, Yb, wv, lane, tpA, tqA, aRe, aIm);
      load_tiles<2>(bp, bq, wv, lane, tpA, tqA);
      compute_ks<1>(Xb, Yb, wv, lane, tpB, tqB, aRe, aIm);
      load_tiles<3>(bp, bq, wv, lane, tpB, tqB);
      compute_ks<2>(Xb, Yb, wv, lane, tpA, tqA, aRe, aIm);
      load_tiles<4>(bp, bq, wv, lane, tpA, tqA);
      compute_ks<3>(Xb, Yb, wv, lane, tpB, tqB, aRe, aIm);
      load_tiles<5>(bp, bq, wv, lane, tpB, tqB);
      compute_ks<4>(Xb, Yb, wv, lane, tpA, tqA, aRe, aIm);
      load_tiles<0>(bp, bq, wv, lane, tpA, tqA);   // prefetch next-iter ks0
      compute_ks<5>(Xb, Yb, wv, lane, tpB, tqB, aRe, aIm);
      load_tiles<1>(bp, bq, wv, lane, tpB, tqB);   // prefetch next-iter ks1

      // epilogue: quad partial = sum_j |w_j|^2 (r4-verbatim)
      float p[4][4];
#pragma unroll
      for (int mf = 0; mf < 4; ++mf)
#pragma unroll
        for (int rr = 0; rr < 4; ++rr) p[mf][rr] = 0.f;
#pragma unroll
      for (int ii = 0; ii < 3; ++ii)
#pragma unroll
        for (int mf = 0; mf < 4; ++mf)
#pragma unroll
          for (int rr = 0; rr < 4; ++rr)
            p[mf][rr] += aRe[ii][mf][rr]*aRe[ii][mf][rr] + aIm[ii][mf][rr]*aIm[ii][mf][rr];
#pragma unroll
      for (int mf = 0; mf < 4; ++mf)
#pragma unroll
        for (int rr = 0; rr < 4; ++rr) {
          float v = p[mf][rr];
          v += __shfl_xor(v, 1);
          v += __shfl_xor(v, 2);
          v += __shfl_xor(v, 4);
          v += __shfl_xor(v, 8);
          p[mf][rr] = v;
        }
      if (r15 == 0) {
        const int g = lane >> 4;
#pragma unroll
        for (int mf = 0; mf < 4; ++mf)
#pragma unroll
          for (int rr = 0; rr < 4; ++rr)
            qp[par][wv][mf*16 + 4*g + rr] = p[mf][rr];
      }
    } else {
      // deferred finalize of the previous rowset (wave 4 only)
      if (wv == 0 && i >= 1) {
        const float quad = qp[1-par][0][lane] + qp[1-par][1][lane]
                         + qp[1-par][2][lane] + qp[1-par][3][lane];
        out[(size_t)(r - gstr) * ROWS + lane] = logf(quad + 1e-12f);
      }
      // produce next rowset into the other buffer
      if (r + gstr < nrs)
        gen_rowset(q, r + gstr, lane, wv, Xls + (1-par)*6144, Yls + (1-par)*6144, mf_r, r15);
    }
    if (r + gstr >= nrs) break;
    ++i; r += gstr;
  }

  // ---- epilogue: finalize the last rowset ----
  __syncthreads();
  if (genw && wv == 0) {
    const int par = i & 1;
    const float quad = qp[par][0][lane] + qp[par][1][lane]
                     + qp[par][2][lane] + qp[par][3][lane];
    out[(size_t)r * ROWS + lane] = logf(quad + 1e-12f);
  }
}

// ---------------- host ----------------
extern "C" void kernel_launch(void* const* d_in, const int* in_sizes, int n_in,
                              void* d_out, int out_size, void* d_ws, size_t ws_size,
                              hipStream_t stream) {
  const float* q   = (const float*)d_in[0];
  const float* Lre = (const float*)d_in[1];
  const float* Lim = (const float*)d_in[2];
  float* out = (float*)d_out;
  uint4* bp = (uint4*)d_ws;
  uint4* bq = bp + NB;
  const int B = in_sizes[0] / 16;
  const int nrs = B / ROWS;           // 4096 rowsets
  poskahler_prep<<<(NB + 255)/256, 256, 0, stream>>>(Lre, Lim, bp, bq);
  poskahler_main<<<256, 512, 0, stream>>>(q, bp, bq, out, nrs);
}

// Round 11
// 52.251 us; speedup vs baseline: 1.3048x; 1.2488x over previous
//
#include <hip/hip_runtime.h>
#include <hip/hip_bf16.h>
#include <utility>

#define DEV static __device__ __forceinline__

typedef __attribute__((ext_vector_type(8))) short bf16x8;
typedef __attribute__((ext_vector_type(4))) float f32x4;

constexpr int KM   = 165;          // number of monomials (deg<=3, 8 complex vars)
constexpr int IT   = 11;           // live i-tiles of 16 (165 -> 176)
constexpr int ITP  = 12;           // padded i-tile count (B layout only)
constexpr int KS   = 6;            // k-steps of 32 -> 192 padded
constexpr int NB   = ITP * KS * 64;
constexpr int ROWS = 64;           // batch rows per block

// ---------------- compile-time POWERS table (itertools.product order) ----------------
struct Pw { unsigned char p[8]; };
struct PwTab { Pw a[KM]; };
constexpr PwTab gen_powers() {
  PwTab t{};
  int idx = 0;
  for (int a0 = 0; a0 <= 3; ++a0)
  for (int a1 = 0; a1 <= 3-a0; ++a1)
  for (int a2 = 0; a2 <= 3-a0-a1; ++a2)
  for (int a3 = 0; a3 <= 3-a0-a1-a2; ++a3)
  for (int a4 = 0; a4 <= 3-a0-a1-a2-a3; ++a4)
  for (int a5 = 0; a5 <= 3-a0-a1-a2-a3-a4; ++a5)
  for (int a6 = 0; a6 <= 3-a0-a1-a2-a3-a4-a5; ++a6)
  for (int a7 = 0; a7 <= 3-a0-a1-a2-a3-a4-a5-a6; ++a7) {
    t.a[idx].p[0] = (unsigned char)a0; t.a[idx].p[1] = (unsigned char)a1;
    t.a[idx].p[2] = (unsigned char)a2; t.a[idx].p[3] = (unsigned char)a3;
    t.a[idx].p[4] = (unsigned char)a4; t.a[idx].p[5] = (unsigned char)a5;
    t.a[idx].p[6] = (unsigned char)a6; t.a[idx].p[7] = (unsigned char)a7;
    ++idx;
  }
  return t;
}
constexpr PwTab PW = gen_powers();

// ---------------- helpers ----------------
DEV unsigned int f2bf(float f) {            // RNE float -> bf16 bits (host-prep path)
  unsigned int u = __builtin_bit_cast(unsigned int, f);
  u += 0x7fffu + ((u >> 16) & 1u);
  return u >> 16;
}
DEV unsigned int pack2_bits(float lo, float hi) { return f2bf(lo) | (f2bf(hi) << 16); }
// single-instruction packed conversion (gen hot path): dst.lo=bf16(lo), dst.hi=bf16(hi)
DEV unsigned int pack2(float lo, float hi) {
  unsigned int r;
  asm("v_cvt_pk_bf16_f32 %0, %1, %2" : "=v"(r) : "v"(lo), "v"(hi));
  return r;
}
DEV float softplusf(float x) { return (x > 20.f) ? x : log1pf(expf(x)); }

// ---- monomial evaluation: ALL table indices are template params (scratch-proof) ----
template<int JJ, int C>
DEV void mono_step(float& r, float& i,
                   const float (&lx)[8][3], const float (&ly)[8][3]) {
  constexpr int pc = PW.a[JJ].p[C];
  if constexpr (pc > 0) {
    const float ar = lx[C][pc-1], ai = ly[C][pc-1];
    const float tr = r*ar - i*ai;
    i = r*ai + i*ar;
    r = tr;
  }
}
template<int JJ>
DEV void mono_eval(float& mr, float& mi,
                   const float (&lx)[8][3], const float (&ly)[8][3]) {
  float r = 1.f, i = 0.f;
  mono_step<JJ,0>(r,i,lx,ly); mono_step<JJ,1>(r,i,lx,ly);
  mono_step<JJ,2>(r,i,lx,ly); mono_step<JJ,3>(r,i,lx,ly);
  mono_step<JJ,4>(r,i,lx,ly); mono_step<JJ,5>(r,i,lx,ly);
  mono_step<JJ,6>(r,i,lx,ly); mono_step<JJ,7>(r,i,lx,ly);
  mr = r; mi = i;
}
template<int JJ>
DEV void mono_eval_guard(float& r, float& i,
                         const float (&lx)[8][3], const float (&ly)[8][3]) {
  if constexpr (JJ < KM) mono_eval<JJ>(r, i, lx, ly);
  else { r = 0.f; i = 0.f; }
}

// ---- gen: chunk T covers monomials [8T, 8T+8) = k-slice (ks=T>>2, g=T&3) ----
template<int T, int... Us>
DEV void gen8(std::integer_sequence<int, Us...>, float (&mr)[8], float (&mi)[8],
              const float (&lx)[8][3], const float (&ly)[8][3]) {
  (mono_eval_guard<8*T + Us>(mr[Us], mi[Us], lx, ly), ...);
}
template<int T>
DEV void gen_chunk(const float (&lx)[8][3], const float (&ly)[8][3],
                   unsigned int* Xf, unsigned int* Yf, int mf, int r15) {
  constexpr int ksv = T >> 2;
  constexpr int gv  = T & 3;
  float mr[8], mi[8];
  gen8<T>(std::make_integer_sequence<int, 8>{}, mr, mi, lx, ly);
  uint4 ux, uy;
  ux.x = pack2(mr[0], mr[1]); ux.y = pack2(mr[2], mr[3]);
  ux.z = pack2(mr[4], mr[5]); ux.w = pack2(mr[6], mr[7]);
  uy.x = pack2(mi[0], mi[1]); uy.y = pack2(mi[2], mi[3]);
  uy.z = pack2(mi[4], mi[5]); uy.w = pack2(mi[6], mi[7]);
  const unsigned int off = (unsigned int)((mf*6 + ksv)*256 + gv*64 + r15*4);
  *(uint4*)&Xf[off] = ux;
  *(uint4*)&Yf[off] = uy;
}
template<int W, int... Ts>
DEV void gen_seq(std::integer_sequence<int, Ts...>,
                 const float (&lx)[8][3], const float (&ly)[8][3],
                 unsigned int* Xf, unsigned int* Yf, int mf, int r15) {
  (gen_chunk<6*W + Ts>(lx, ly, Xf, Yf, mf, r15), ...);
}
template<int W>
DEV void gen_wave(const float (&lx)[8][3], const float (&ly)[8][3],
                  unsigned int* Xf, unsigned int* Yf, int mf, int r15) {
  gen_seq<W>(std::make_integer_sequence<int, 6>{}, lx, ly, Xf, Yf, mf, r15);
}

// ---------------- prep: conj(L)^T -> bf16 B-operand fragments (triangular) ----------
__global__ void __launch_bounds__(256) poskahler_prep(
    const float* __restrict__ Lre, const float* __restrict__ Lim,
    uint4* __restrict__ bp, uint4* __restrict__ bq) {
  const int tid = blockIdx.x * 256 + threadIdx.x;
  if (tid >= NB) return;
  const int lane = tid & 63;
  const int it = (tid >> 6) / KS;
  const int ks = (tid >> 6) % KS;
  const int j  = it * 16 + (lane & 15);
  const int ib = ks * 32 + ((lane >> 4) << 3);
  float pr[8], qr[8];
#pragma unroll
  for (int e = 0; e < 8; ++e) { pr[e] = 0.f; qr[e] = 0.f; }
  if (j < KM) {
#pragma unroll
    for (int e = 0; e < 8; ++e) {
      const int i = ib + e;
      if (i < KM) {
        if (i > j)      { pr[e] = Lre[i*KM + j]; qr[e] = -Lim[i*KM + j]; }
        else if (i == j){ pr[e] = softplusf(Lre[j*KM + j]) + 0.001f; }
      }
    }
  }
  uint4 up, uq;
  up.x = pack2_bits(pr[0], pr[1]); up.y = pack2_bits(pr[2], pr[3]);
  up.z = pack2_bits(pr[4], pr[5]); up.w = pack2_bits(pr[6], pr[7]);
  uq.x = pack2_bits(qr[0], qr[1]); uq.y = pack2_bits(qr[2], qr[3]);
  uq.z = pack2_bits(qr[4], qr[5]); uq.w = pack2_bits(qr[6], qr[7]);
  bp[tid] = up;
  bq[tid] = uq;
}

// ---------------- main k-loop building blocks (fully static) ----------------
template<int KSv>
DEV void load_tiles(const uint4* __restrict__ bp, const uint4* __restrict__ bq,
                    int wv, int lane, uint4 (&tp)[3], uint4 (&tq)[3]) {
#pragma unroll
  for (int ii = 0; ii < 3; ++ii) {
    const int it = 4*ii + wv;
    if (it <= 2*KSv + 1 && it < IT) {
      const int fs = (it*KS + KSv)*64 + lane;
      tp[ii] = bp[fs];
      tq[ii] = bq[fs];
    }
  }
}

template<int KSv>
DEV void compute_ks(const unsigned int* Xf, const unsigned int* Yf,
                    int wv, int lane,
                    const uint4 (&tp)[3], const uint4 (&tq)[3],
                    float (&aRe)[3][4][4], float (&aIm)[3][4][4]) {
  bf16x8 xf[4], yf[4];
#pragma unroll
  for (int mf = 0; mf < 4; ++mf) {
    const unsigned int off = (unsigned int)((mf*6 + KSv)*256) + (unsigned int)lane*4;
    xf[mf] = __builtin_bit_cast(bf16x8, *(const uint4*)&Xf[off]);
    yf[mf] = __builtin_bit_cast(bf16x8, *(const uint4*)&Yf[off]);
  }
#pragma unroll
  for (int ii = 0; ii < 3; ++ii) {
    const int it = 4*ii + wv;
    if (it <= 2*KSv + 1 && it < IT) {
      const uint4 up = tp[ii];
      const uint4 uq = tq[ii];
      uint4 un;
      un.x = uq.x ^ 0x80008000u; un.y = uq.y ^ 0x80008000u;
      un.z = uq.z ^ 0x80008000u; un.w = uq.w ^ 0x80008000u;
      const bf16x8 vp = __builtin_bit_cast(bf16x8, up);
      const bf16x8 vq = __builtin_bit_cast(bf16x8, uq);
      const bf16x8 vn = __builtin_bit_cast(bf16x8, un);
#pragma unroll
      for (int mf = 0; mf < 4; ++mf) {
        f32x4 cre = { aRe[ii][mf][0], aRe[ii][mf][1], aRe[ii][mf][2], aRe[ii][mf][3] };
        f32x4 cim = { aIm[ii][mf][0], aIm[ii][mf][1], aIm[ii][mf][2], aIm[ii][mf][3] };
        // wre = P x + Q y ; wim = P y - Q x
        cre = __builtin_amdgcn_mfma_f32_16x16x32_bf16(xf[mf], vp, cre, 0, 0, 0);
        cre = __builtin_amdgcn_mfma_f32_16x16x32_bf16(yf[mf], vq, cre, 0, 0, 0);
        cim = __builtin_amdgcn_mfma_f32_16x16x32_bf16(yf[mf], vp, cim, 0, 0, 0);
        cim = __builtin_amdgcn_mfma_f32_16x16x32_bf16(xf[mf], vn, cim, 0, 0, 0);
#pragma unroll
        for (int rr = 0; rr < 4; ++rr) { aRe[ii][mf][rr] = cre[rr]; aIm[ii][mf][rr] = cim[rr]; }
      }
    }
  }
}

// ---------------- main: monomials -> w = L^H z via MFMA -> log(|w|^2) --------------
__global__ void __launch_bounds__(256, 2) poskahler_main(
    const float* __restrict__ q,
    const uint4* __restrict__ bp, const uint4* __restrict__ bq,
    float* __restrict__ out) {
  // fragment-ordered monomial store: region (mf*6+ks)*256 dwords, lane entry lane*4
  __shared__ __align__(16) unsigned int Xf[6144];
  __shared__ __align__(16) unsigned int Yf[6144];
  __shared__ float qpart[4][ROWS];

  const int t     = threadIdx.x;
  const int lane  = t & 63;
  const int wv    = t >> 6;                 // 4 waves
  const int bbase = blockIdx.x * ROWS;
  const int mf_r  = lane >> 4;              // gen: this thread's row -> frag mf
  const int r15   = lane & 15;

  // ---- q row load FIRST (HBM latency starts draining before everything else) ----
  const float* qr = q + (size_t)(bbase + lane) * 16;
  const float4 q0 = ((const float4*)qr)[0];
  const float4 q1 = ((const float4*)qr)[1];
  const float4 q2 = ((const float4*)qr)[2];
  const float4 q3 = ((const float4*)qr)[3];

  // ---- B-tile prefetch for ks=0,1 (latency hides under gen phase) ----
  uint4 tpA[3] = {}, tqA[3] = {}, tpB[3] = {}, tqB[3] = {};
  load_tiles<0>(bp, bq, wv, lane, tpA, tqA);
  load_tiles<1>(bp, bq, wv, lane, tpB, tqB);

  // ---- monomial generation: wave wv covers monomials [48wv, 48wv+48) of each row --
  {
    const float xs[8] = {q0.x,q0.y,q0.z,q0.w,q1.x,q1.y,q1.z,q1.w};
    const float ys[8] = {q2.x,q2.y,q2.z,q2.w,q3.x,q3.y,q3.z,q3.w};
    float lx[8][3], ly[8][3];
#pragma unroll
    for (int c = 0; c < 8; ++c) {
      const float xr = xs[c], yi = ys[c];
      lx[c][0] = xr;             ly[c][0] = yi;
      lx[c][1] = xr*xr - yi*yi;  ly[c][1] = 2.f*xr*yi;
      lx[c][2] = lx[c][1]*xr - ly[c][1]*yi;
      ly[c][2] = lx[c][1]*yi + ly[c][1]*xr;
    }
    switch (wv) {
      case 0: gen_wave<0>(lx, ly, Xf, Yf, mf_r, r15); break;
      case 1: gen_wave<1>(lx, ly, Xf, Yf, mf_r, r15); break;
      case 2: gen_wave<2>(lx, ly, Xf, Yf, mf_r, r15); break;
      default: gen_wave<3>(lx, ly, Xf, Yf, mf_r, r15); break;
    }
  }
  __syncthreads();

  // ---- w = L^H z : ks fully unrolled, double-buffered B tiles ----
  float aRe[3][4][4], aIm[3][4][4];
#pragma unroll
  for (int ii = 0; ii < 3; ++ii)
#pragma unroll
    for (int mf = 0; mf < 4; ++mf)
#pragma unroll
      for (int rr = 0; rr < 4; ++rr) { aRe[ii][mf][rr] = 0.f; aIm[ii][mf][rr] = 0.f; }

  compute_ks<0>(Xf, Yf, wv, lane, tpA, tqA, aRe, aIm);
  load_tiles<2>(bp, bq, wv, lane, tpA, tqA);
  compute_ks<1>(Xf, Yf, wv, lane, tpB, tqB, aRe, aIm);
  load_tiles<3>(bp, bq, wv, lane, tpB, tqB);
  compute_ks<2>(Xf, Yf, wv, lane, tpA, tqA, aRe, aIm);
  load_tiles<4>(bp, bq, wv, lane, tpA, tqA);
  compute_ks<3>(Xf, Yf, wv, lane, tpB, tqB, aRe, aIm);
  load_tiles<5>(bp, bq, wv, lane, tpB, tqB);
  compute_ks<4>(Xf, Yf, wv, lane, tpA, tqA, aRe, aIm);
  compute_ks<5>(Xf, Yf, wv, lane, tpB, tqB, aRe, aIm);

  // ---- epilogue: quad partial = sum_j |w_j|^2 ----
  float p[4][4];
#pragma unroll
  for (int mf = 0; mf < 4; ++mf)
#pragma unroll
    for (int rr = 0; rr < 4; ++rr) p[mf][rr] = 0.f;

#pragma unroll
  for (int ii = 0; ii < 3; ++ii)
#pragma unroll
    for (int mf = 0; mf < 4; ++mf)
#pragma unroll
      for (int rr = 0; rr < 4; ++rr)
        p[mf][rr] += aRe[ii][mf][rr]*aRe[ii][mf][rr] + aIm[ii][mf][rr]*aIm[ii][mf][rr];

#pragma unroll
  for (int mf = 0; mf < 4; ++mf)
#pragma unroll
    for (int rr = 0; rr < 4; ++rr) {
      float v = p[mf][rr];
      v += __shfl_xor(v, 1);
      v += __shfl_xor(v, 2);
      v += __shfl_xor(v, 4);
      v += __shfl_xor(v, 8);
      p[mf][rr] = v;
    }

  if (r15 == 0) {
    const int g = lane >> 4;
#pragma unroll
    for (int mf = 0; mf < 4; ++mf)
#pragma unroll
      for (int rr = 0; rr < 4; ++rr)
        qpart[wv][mf*16 + 4*g + rr] = p[mf][rr];
  }
  __syncthreads();
  if (t < ROWS) {
    const float quad = qpart[0][t] + qpart[1][t] + qpart[2][t] + qpart[3][t];
    out[bbase + t] = logf(quad + 1e-12f);
  }
}

// ---------------- host ----------------
extern "C" void kernel_launch(void* const* d_in, const int* in_sizes, int n_in,
                              void* d_out, int out_size, void* d_ws, size_t ws_size,
                              hipStream_t stream) {
  const float* q   = (const float*)d_in[0];
  const float* Lre = (const float*)d_in[1];
  const float* Lim = (const float*)d_in[2];
  float* out = (float*)d_out;
  uint4* bp = (uint4*)d_ws;
  uint4* bq = bp + NB;
  const int B = in_sizes[0] / 16;
  poskahler_prep<<<(NB + 255)/256, 256, 0, stream>>>(Lre, Lim, bp, bq);
  poskahler_main<<<B / ROWS, 256, 0, stream>>>(q, bp, bq, out);
}